// Round 4
// baseline (16707.951 us; speedup 1.0000x reference)
//
#include <hip/hip_runtime.h>

#pragma clang fp contract(off)

#define BATCH 2
#define NPTS  16384
#define SS    4096
#define NSAMP 32
#define CIN   64

// ---------------------------------------------------------------------------
// prep: transpose features (B,64,N) -> (B,N,64); pack W0 (64x67) -> (64x68, 0-pad)
// ---------------------------------------------------------------------------
__global__ __launch_bounds__(256) void prep_kernel(
    const float* __restrict__ feat, const float* __restrict__ W0,
    float* __restrict__ ftr, float* __restrict__ W0p)
{
    __shared__ float tl[64][65];
    const int t = threadIdx.x;
    const int blk = blockIdx.x;
    if (blk < BATCH * (NPTS / 64)) {
        const int b  = blk / (NPTS / 64);
        const int n0 = (blk % (NPTS / 64)) * 64;
        #pragma unroll
        for (int k = 0; k < 16; ++k) {
            int c = k * 4 + (t >> 6);
            int n = t & 63;
            tl[c][n] = feat[((size_t)b * CIN + c) * NPTS + n0 + n];
        }
        __syncthreads();
        #pragma unroll
        for (int k = 0; k < 16; ++k) {
            int n = k * 4 + (t >> 6);
            int c = t & 63;
            ftr[((size_t)b * NPTS + n0 + n) * CIN + c] = tl[c][n];
        }
    } else {
        for (int i = t; i < 64 * 68; i += 256) {
            int r = i / 68, c = i % 68;
            W0p[i] = (c < 67) ? W0[r * 67 + c] : 0.f;
        }
    }
}

// ---------------------------------------------------------------------------
// FPS: one block per batch. 1024 threads x 16 points in registers.
// Exact FP semantics: no FMA contraction, sum order ((dx^2+dy^2)+dz^2),
// argmax tie-break = smallest index (numpy first-occurrence).
// ---------------------------------------------------------------------------
__global__ __launch_bounds__(1024) void fps_kernel(
    const float* __restrict__ xyz, float* __restrict__ newxyz)
{
    #pragma clang fp contract(off)
    const int b = blockIdx.x;
    const int t = threadIdx.x;
    const float* xb = xyz + (size_t)b * NPTS * 3;

    float px[16], py[16], pz[16], md[16];
    #pragma unroll
    for (int k = 0; k < 16; ++k) {
        int p = (k << 10) + t;
        px[k] = xb[p * 3 + 0];
        py[k] = xb[p * 3 + 1];
        pz[k] = xb[p * 3 + 2];
        md[k] = 1e10f;
    }

    __shared__ float4 s_v[2][16];
    __shared__ int    s_i[2][16];

    float lx = xb[0], ly = xb[1], lz = xb[2];
    if (t == 0) {
        float* o = newxyz + (size_t)b * SS * 3;
        o[0] = lx; o[1] = ly; o[2] = lz;
    }

    for (int s = 1; s < SS; ++s) {
        float bv = -1.f;
        int bi = 0, bk = 0;
        #pragma unroll
        for (int k = 0; k < 16; ++k) {
            float dx = px[k] - lx, dy = py[k] - ly, dz = pz[k] - lz;
            float d = (dx * dx + dy * dy) + dz * dz;   // contract(off): exact order
            float m = md[k];
            m = d < m ? d : m;
            md[k] = m;
            if (m > bv) { bv = m; bi = (k << 10) + t; bk = k; }
        }
        // select local winner coords (static-index cndmask chain; no scratch)
        float sx = px[0], sy = py[0], sz = pz[0];
        #pragma unroll
        for (int k = 1; k < 16; ++k)
            if (bk == k) { sx = px[k]; sy = py[k]; sz = pz[k]; }

        // wave butterfly argmax carrying coords
        #pragma unroll
        for (int m = 1; m < 64; m <<= 1) {
            float ov = __shfl_xor(bv, m);
            int   oi = __shfl_xor(bi, m);
            float ox = __shfl_xor(sx, m);
            float oy = __shfl_xor(sy, m);
            float oz = __shfl_xor(sz, m);
            bool take = (ov > bv) || (ov == bv && oi < bi);
            if (take) { bv = ov; bi = oi; sx = ox; sy = oy; sz = oz; }
        }

        const int pb = s & 1;
        if ((t & 63) == 0) {
            s_v[pb][t >> 6] = make_float4(bv, sx, sy, sz);
            s_i[pb][t >> 6] = bi;
        }
        __syncthreads();

        // every wave redundantly reduces the 16 wave-winners (no 2nd barrier)
        float4 rv = s_v[pb][t & 15];
        int    ri = s_i[pb][t & 15];
        #pragma unroll
        for (int m = 1; m < 16; m <<= 1) {
            float o0 = __shfl_xor(rv.x, m);
            float o1 = __shfl_xor(rv.y, m);
            float o2 = __shfl_xor(rv.z, m);
            float o3 = __shfl_xor(rv.w, m);
            int   oi = __shfl_xor(ri, m);
            bool take = (o0 > rv.x) || (o0 == rv.x && oi < ri);
            if (take) { rv.x = o0; rv.y = o1; rv.z = o2; rv.w = o3; ri = oi; }
        }
        lx = rv.y; ly = rv.z; lz = rv.w;
        if (t == 0) {
            float* o = newxyz + ((size_t)b * SS + s) * 3;
            o[0] = lx; o[1] = ly; o[2] = lz;
        }
    }
}

// ---------------------------------------------------------------------------
// Ball query: one wave per query. First NSAMP valid indices in index order,
// pad with first valid, cnt flag. Exact FP compare semantics.
// ---------------------------------------------------------------------------
__global__ __launch_bounds__(256) void bq_kernel(
    const float* __restrict__ xyz, const float* __restrict__ newxyz,
    int* __restrict__ idxout, int* __restrict__ cntout)
{
    #pragma clang fp contract(off)
    const int lane = threadIdx.x & 63;
    const int q = blockIdx.x * 4 + (threadIdx.x >> 6);
    const int b = q >> 12;
    const float r2 = (float)(0.08 * 0.08);
    const float cx = newxyz[q * 3 + 0];
    const float cy = newxyz[q * 3 + 1];
    const float cz = newxyz[q * 3 + 2];
    const float* xb = xyz + (size_t)b * NPTS * 3;

    int found = 0;
    int idx0 = 0;
    for (int base = 0; base < NPTS; base += 64) {
        int p = base + lane;
        float dx = xb[p * 3 + 0] - cx;
        float dy = xb[p * 3 + 1] - cy;
        float dz = xb[p * 3 + 2] - cz;
        float d2 = (dx * dx + dy * dy) + dz * dz;   // contract(off)
        bool valid = d2 < r2;
        unsigned long long mask = __ballot(valid);
        if (mask) {
            if (found == 0) idx0 = base + (__ffsll(mask) - 1);
            int rank = found + __popcll(mask & ((1ull << lane) - 1ull));
            if (valid && rank < NSAMP) idxout[(size_t)q * NSAMP + rank] = p;
            found += (int)__popcll(mask);
            if (found >= NSAMP) break;
        }
    }
    if (found < NSAMP) {
        int pad = (found > 0) ? idx0 : 0;
        if (found + lane < NSAMP) idxout[(size_t)q * NSAMP + found + lane] = pad;
    }
    if (lane == 0) cntout[q] = found;
}

// ---------------------------------------------------------------------------
// Fused gather + 3-layer 1x1-conv MLP + masked max-pool.
// One wave per group; X/Y tiles in LDS (row stride 36 floats, conflict-free
// float4 access); weights streamed from global (L1-resident); explicit fmaf.
// ---------------------------------------------------------------------------
__global__ __launch_bounds__(128) void mlp_kernel(
    const float* __restrict__ xyz, const float* __restrict__ newxyz,
    const float* __restrict__ ftr, const int* __restrict__ idxbuf,
    const int* __restrict__ cntbuf, const float* __restrict__ W0p,
    const float* __restrict__ b0, const float* __restrict__ W1,
    const float* __restrict__ b1, const float* __restrict__ W2,
    const float* __restrict__ b2, float* __restrict__ outfeat)
{
    __shared__ float sX[2][68 * 36];
    __shared__ float sY[2][64 * 36];
    const int w    = threadIdx.x >> 6;
    const int lane = threadIdx.x & 63;
    const int g = blockIdx.x * 2 + w;
    const int b = g >> 12;
    const int s = g & (SS - 1);
    float* X = sX[w];
    float* Y = sY[w];

    const int n = lane & 31, h = lane >> 5;
    const int pidx = idxbuf[(size_t)g * NSAMP + n];
    const float cx = newxyz[g * 3 + 0];
    const float cy = newxyz[g * 3 + 1];
    const float cz = newxyz[g * 3 + 2];

    if (h == 0) {
        const float* p = xyz + ((size_t)b * NPTS + pidx) * 3;
        X[0 * 36 + n] = p[0] - cx;
        X[1 * 36 + n] = p[1] - cy;
        X[2 * 36 + n] = p[2] - cz;
        X[67 * 36 + n] = 0.f;
    }
    {
        const float4* f4 = (const float4*)(ftr + ((size_t)b * NPTS + pidx) * CIN + h * 32);
        #pragma unroll
        for (int j = 0; j < 8; ++j) {
            float4 v = f4[j];
            int c = 3 + h * 32 + j * 4;
            X[(c + 0) * 36 + n] = v.x;
            X[(c + 1) * 36 + n] = v.y;
            X[(c + 2) * 36 + n] = v.z;
            X[(c + 3) * 36 + n] = v.w;
        }
    }
    __syncthreads();

    const int og = lane >> 3, ng = lane & 7;

    // ---- Layer 0: 67(->68) -> 64
    float acc0[8][4];
    #pragma unroll
    for (int j = 0; j < 8; ++j)
        #pragma unroll
        for (int nn = 0; nn < 4; ++nn) acc0[j][nn] = 0.f;
    for (int cb = 0; cb < 17; ++cb) {
        const int c = cb * 4;
        float4 xr0 = *(const float4*)&X[(c + 0) * 36 + ng * 4];
        float4 xr1 = *(const float4*)&X[(c + 1) * 36 + ng * 4];
        float4 xr2 = *(const float4*)&X[(c + 2) * 36 + ng * 4];
        float4 xr3 = *(const float4*)&X[(c + 3) * 36 + ng * 4];
        #pragma unroll
        for (int j = 0; j < 8; ++j) {
            float4 wv = *(const float4*)&W0p[(size_t)(og * 8 + j) * 68 + c];
            acc0[j][0] = fmaf(wv.x, xr0.x, acc0[j][0]);
            acc0[j][1] = fmaf(wv.x, xr0.y, acc0[j][1]);
            acc0[j][2] = fmaf(wv.x, xr0.z, acc0[j][2]);
            acc0[j][3] = fmaf(wv.x, xr0.w, acc0[j][3]);
            acc0[j][0] = fmaf(wv.y, xr1.x, acc0[j][0]);
            acc0[j][1] = fmaf(wv.y, xr1.y, acc0[j][1]);
            acc0[j][2] = fmaf(wv.y, xr1.z, acc0[j][2]);
            acc0[j][3] = fmaf(wv.y, xr1.w, acc0[j][3]);
            acc0[j][0] = fmaf(wv.z, xr2.x, acc0[j][0]);
            acc0[j][1] = fmaf(wv.z, xr2.y, acc0[j][1]);
            acc0[j][2] = fmaf(wv.z, xr2.z, acc0[j][2]);
            acc0[j][3] = fmaf(wv.z, xr2.w, acc0[j][3]);
            acc0[j][0] = fmaf(wv.w, xr3.x, acc0[j][0]);
            acc0[j][1] = fmaf(wv.w, xr3.y, acc0[j][1]);
            acc0[j][2] = fmaf(wv.w, xr3.z, acc0[j][2]);
            acc0[j][3] = fmaf(wv.w, xr3.w, acc0[j][3]);
        }
    }
    #pragma unroll
    for (int j = 0; j < 8; ++j) {
        const float bv = b0[og * 8 + j];
        float4 yv;
        yv.x = fmaxf(acc0[j][0] + bv, 0.f);
        yv.y = fmaxf(acc0[j][1] + bv, 0.f);
        yv.z = fmaxf(acc0[j][2] + bv, 0.f);
        yv.w = fmaxf(acc0[j][3] + bv, 0.f);
        *(float4*)&Y[(og * 8 + j) * 36 + ng * 4] = yv;
    }
    __syncthreads();

    // ---- Layer 1: 64 -> 64  (Y -> X rows 0..63)
    float acc1[8][4];
    #pragma unroll
    for (int j = 0; j < 8; ++j)
        #pragma unroll
        for (int nn = 0; nn < 4; ++nn) acc1[j][nn] = 0.f;
    for (int cb = 0; cb < 16; ++cb) {
        const int c = cb * 4;
        float4 xr0 = *(const float4*)&Y[(c + 0) * 36 + ng * 4];
        float4 xr1 = *(const float4*)&Y[(c + 1) * 36 + ng * 4];
        float4 xr2 = *(const float4*)&Y[(c + 2) * 36 + ng * 4];
        float4 xr3 = *(const float4*)&Y[(c + 3) * 36 + ng * 4];
        #pragma unroll
        for (int j = 0; j < 8; ++j) {
            float4 wv = *(const float4*)&W1[(size_t)(og * 8 + j) * 64 + c];
            acc1[j][0] = fmaf(wv.x, xr0.x, acc1[j][0]);
            acc1[j][1] = fmaf(wv.x, xr0.y, acc1[j][1]);
            acc1[j][2] = fmaf(wv.x, xr0.z, acc1[j][2]);
            acc1[j][3] = fmaf(wv.x, xr0.w, acc1[j][3]);
            acc1[j][0] = fmaf(wv.y, xr1.x, acc1[j][0]);
            acc1[j][1] = fmaf(wv.y, xr1.y, acc1[j][1]);
            acc1[j][2] = fmaf(wv.y, xr1.z, acc1[j][2]);
            acc1[j][3] = fmaf(wv.y, xr1.w, acc1[j][3]);
            acc1[j][0] = fmaf(wv.z, xr2.x, acc1[j][0]);
            acc1[j][1] = fmaf(wv.z, xr2.y, acc1[j][1]);
            acc1[j][2] = fmaf(wv.z, xr2.z, acc1[j][2]);
            acc1[j][3] = fmaf(wv.z, xr2.w, acc1[j][3]);
            acc1[j][0] = fmaf(wv.w, xr3.x, acc1[j][0]);
            acc1[j][1] = fmaf(wv.w, xr3.y, acc1[j][1]);
            acc1[j][2] = fmaf(wv.w, xr3.z, acc1[j][2]);
            acc1[j][3] = fmaf(wv.w, xr3.w, acc1[j][3]);
        }
    }
    __syncthreads();   // X rows are about to be overwritten; Y reads done
    #pragma unroll
    for (int j = 0; j < 8; ++j) {
        const float bv = b1[og * 8 + j];
        float4 yv;
        yv.x = fmaxf(acc1[j][0] + bv, 0.f);
        yv.y = fmaxf(acc1[j][1] + bv, 0.f);
        yv.z = fmaxf(acc1[j][2] + bv, 0.f);
        yv.w = fmaxf(acc1[j][3] + bv, 0.f);
        *(float4*)&X[(og * 8 + j) * 36 + ng * 4] = yv;
    }
    __syncthreads();

    // ---- Layer 2: 64 -> 128 (X rows 0..63 -> registers) + masked max-pool
    float acc2[16][4];
    #pragma unroll
    for (int j = 0; j < 16; ++j)
        #pragma unroll
        for (int nn = 0; nn < 4; ++nn) acc2[j][nn] = 0.f;
    for (int cb = 0; cb < 16; ++cb) {
        const int c = cb * 4;
        float4 xr0 = *(const float4*)&X[(c + 0) * 36 + ng * 4];
        float4 xr1 = *(const float4*)&X[(c + 1) * 36 + ng * 4];
        float4 xr2 = *(const float4*)&X[(c + 2) * 36 + ng * 4];
        float4 xr3 = *(const float4*)&X[(c + 3) * 36 + ng * 4];
        #pragma unroll
        for (int j = 0; j < 16; ++j) {
            float4 wv = *(const float4*)&W2[(size_t)(og * 16 + j) * 64 + c];
            acc2[j][0] = fmaf(wv.x, xr0.x, acc2[j][0]);
            acc2[j][1] = fmaf(wv.x, xr0.y, acc2[j][1]);
            acc2[j][2] = fmaf(wv.x, xr0.z, acc2[j][2]);
            acc2[j][3] = fmaf(wv.x, xr0.w, acc2[j][3]);
            acc2[j][0] = fmaf(wv.y, xr1.x, acc2[j][0]);
            acc2[j][1] = fmaf(wv.y, xr1.y, acc2[j][1]);
            acc2[j][2] = fmaf(wv.y, xr1.z, acc2[j][2]);
            acc2[j][3] = fmaf(wv.y, xr1.w, acc2[j][3]);
            acc2[j][0] = fmaf(wv.z, xr2.x, acc2[j][0]);
            acc2[j][1] = fmaf(wv.z, xr2.y, acc2[j][1]);
            acc2[j][2] = fmaf(wv.z, xr2.z, acc2[j][2]);
            acc2[j][3] = fmaf(wv.z, xr2.w, acc2[j][3]);
            acc2[j][0] = fmaf(wv.w, xr3.x, acc2[j][0]);
            acc2[j][1] = fmaf(wv.w, xr3.y, acc2[j][1]);
            acc2[j][2] = fmaf(wv.w, xr3.z, acc2[j][2]);
            acc2[j][3] = fmaf(wv.w, xr3.w, acc2[j][3]);
        }
    }

    const int cnt = cntbuf[g];
    const float msk = (cnt > 0) ? 1.f : 0.f;
    float* ob = outfeat + ((size_t)b * 128) * SS + s;
    float mj[16];
    #pragma unroll
    for (int j = 0; j < 16; ++j) {
        const float bv = b2[og * 16 + j];
        float v0 = fmaxf(acc2[j][0] + bv, acc2[j][1] + bv);
        float v1 = fmaxf(acc2[j][2] + bv, acc2[j][3] + bv);
        float v = fmaxf(fmaxf(v0, v1), 0.f);
        v = fmaxf(v, __shfl_xor(v, 1));
        v = fmaxf(v, __shfl_xor(v, 2));
        v = fmaxf(v, __shfl_xor(v, 4));
        mj[j] = v * msk;
    }
    if (ng == 0) {
        #pragma unroll
        for (int j = 0; j < 16; ++j)
            ob[(size_t)(og * 16 + j) * SS] = mj[j];
    }
}

// ---------------------------------------------------------------------------
extern "C" void kernel_launch(void* const* d_in, const int* in_sizes, int n_in,
                              void* d_out, int out_size, void* d_ws, size_t ws_size,
                              hipStream_t stream)
{
    (void)in_sizes; (void)n_in; (void)out_size; (void)ws_size;
    const float* xyz  = (const float*)d_in[0];
    const float* feat = (const float*)d_in[1];
    const float* W0 = (const float*)d_in[2];
    const float* b0 = (const float*)d_in[3];
    const float* W1 = (const float*)d_in[4];
    const float* b1 = (const float*)d_in[5];
    const float* W2 = (const float*)d_in[6];
    const float* b2 = (const float*)d_in[7];

    float* out     = (float*)d_out;
    float* newxyz  = out;                          // (B,S,3)
    float* outfeat = out + (size_t)BATCH * SS * 3; // (B,128,S)

    char* ws = (char*)d_ws;
    float* ftr = (float*)ws;                                   // B*N*64 f32 (8 MB)
    size_t off = (size_t)BATCH * NPTS * CIN * sizeof(float);
    int* idxbuf = (int*)(ws + off); off += (size_t)BATCH * SS * NSAMP * sizeof(int);
    int* cntbuf = (int*)(ws + off); off += (size_t)BATCH * SS * sizeof(int);
    float* W0p  = (float*)(ws + off);

    prep_kernel<<<dim3(BATCH * (NPTS / 64) + 1), dim3(256), 0, stream>>>(feat, W0, ftr, W0p);
    fps_kernel<<<dim3(BATCH), dim3(1024), 0, stream>>>(xyz, newxyz);
    bq_kernel<<<dim3(BATCH * SS / 4), dim3(256), 0, stream>>>(xyz, newxyz, idxbuf, cntbuf);
    mlp_kernel<<<dim3(BATCH * SS / 2), dim3(128), 0, stream>>>(
        xyz, newxyz, ftr, idxbuf, cntbuf, W0p, b0, W1, b1, W2, b2, outfeat);
}

// Round 5
// 8850.751 us; speedup vs baseline: 1.8877x; 1.8877x over previous
//
#include <hip/hip_runtime.h>

#pragma clang fp contract(off)

#define BATCH 2
#define NPTS  16384
#define SS    4096
#define NSAMP 32
#define CIN   64

// ---------------------------------------------------------------------------
// prep: transpose features (B,64,N) -> (B,N,64); pack W0 (64x67) -> (64x68, 0-pad)
// ---------------------------------------------------------------------------
__global__ __launch_bounds__(256) void prep_kernel(
    const float* __restrict__ feat, const float* __restrict__ W0,
    float* __restrict__ ftr, float* __restrict__ W0p)
{
    __shared__ float tl[64][65];
    const int t = threadIdx.x;
    const int blk = blockIdx.x;
    if (blk < BATCH * (NPTS / 64)) {
        const int b  = blk / (NPTS / 64);
        const int n0 = (blk % (NPTS / 64)) * 64;
        #pragma unroll
        for (int k = 0; k < 16; ++k) {
            int c = k * 4 + (t >> 6);
            int n = t & 63;
            tl[c][n] = feat[((size_t)b * CIN + c) * NPTS + n0 + n];
        }
        __syncthreads();
        #pragma unroll
        for (int k = 0; k < 16; ++k) {
            int n = k * 4 + (t >> 6);
            int c = t & 63;
            ftr[((size_t)b * NPTS + n0 + n) * CIN + c] = tl[c][n];
        }
    } else {
        for (int i = t; i < 64 * 68; i += 256) {
            int r = i / 68, c = i % 68;
            W0p[i] = (c < 67) ? W0[r * 67 + c] : 0.f;
        }
    }
}

// ---------------------------------------------------------------------------
// FPS: one block per batch, 1024 threads x 16 points in REGISTERS.
// __launch_bounds__(1024, 4): 4 waves/EU = exactly 1 block/CU -> 128-VGPR
// budget; the 64-VGPR point arrays stay in registers (r4 showed VGPR=64 =>
// scratch spill at 4.0us/step).
// Reductions carry only (bv, bi); winner coords re-loaded from global
// (bit-identical source). Exact FP semantics: contract off, ((dx2+dy2)+dz2),
// argmax tie-break = smallest index.
// ---------------------------------------------------------------------------
__global__ __launch_bounds__(1024, 4) void fps_kernel(
    const float* __restrict__ xyz, float* __restrict__ newxyz)
{
    #pragma clang fp contract(off)
    const int b = blockIdx.x;
    const int t = threadIdx.x;
    const float* xb = xyz + (size_t)b * NPTS * 3;

    float px[16], py[16], pz[16], md[16];
    #pragma unroll
    for (int k = 0; k < 16; ++k) {
        int p = (k << 10) + t;
        px[k] = xb[p * 3 + 0];
        py[k] = xb[p * 3 + 1];
        pz[k] = xb[p * 3 + 2];
        md[k] = 1e10f;
    }

    __shared__ float2 s_w[2][16];   // (best_val, best_idx as bits) per wave

    float lx = xb[0], ly = xb[1], lz = xb[2];
    if (t == 0) {
        float* o = newxyz + (size_t)b * SS * 3;
        o[0] = lx; o[1] = ly; o[2] = lz;
    }

    for (int s = 1; s < SS; ++s) {
        float bv = -1.f;
        int bi = 0;
        #pragma unroll
        for (int k = 0; k < 16; ++k) {
            float dx = px[k] - lx, dy = py[k] - ly, dz = pz[k] - lz;
            float d = (dx * dx + dy * dy) + dz * dz;   // contract(off): exact order
            float m = md[k];
            m = d < m ? d : m;
            md[k] = m;
            if (m > bv) { bv = m; bi = (k << 10) + t; }
        }

        // wave butterfly argmax, payload (bv, bi) only
        #pragma unroll
        for (int m = 1; m < 64; m <<= 1) {
            float ov = __shfl_xor(bv, m);
            int   oi = __shfl_xor(bi, m);
            bool take = (ov > bv) || (ov == bv && oi < bi);
            if (take) { bv = ov; bi = oi; }
        }

        const int pb = s & 1;
        if ((t & 63) == 0)
            s_w[pb][t >> 6] = make_float2(bv, __int_as_float(bi));
        __syncthreads();

        // every wave redundantly reduces the 16 wave-winners (no 2nd barrier;
        // double buffer pb prevents WAR across the single barrier)
        float2 rw = s_w[pb][t & 15];
        float rv = rw.x;
        int   ri = __float_as_int(rw.y);
        #pragma unroll
        for (int m = 1; m < 16; m <<= 1) {
            float ov = __shfl_xor(rv, m);
            int   oi = __shfl_xor(ri, m);
            bool take = (ov > rv) || (ov == rv && oi < ri);
            if (take) { rv = ov; ri = oi; }
        }

        // winner coords from global (same memory the carried regs came from;
        // wave-uniform address -> scalar load, L2-resident)
        const int wi = __builtin_amdgcn_readfirstlane(ri);
        lx = xb[wi * 3 + 0];
        ly = xb[wi * 3 + 1];
        lz = xb[wi * 3 + 2];
        if (t == 0) {
            float* o = newxyz + ((size_t)b * SS + s) * 3;
            o[0] = lx; o[1] = ly; o[2] = lz;
        }
    }
}

// ---------------------------------------------------------------------------
// Ball query: one wave per query. First NSAMP valid indices in index order,
// pad with first valid, cnt flag. Exact FP compare semantics.
// ---------------------------------------------------------------------------
__global__ __launch_bounds__(256) void bq_kernel(
    const float* __restrict__ xyz, const float* __restrict__ newxyz,
    int* __restrict__ idxout, int* __restrict__ cntout)
{
    #pragma clang fp contract(off)
    const int lane = threadIdx.x & 63;
    const int q = blockIdx.x * 4 + (threadIdx.x >> 6);
    const int b = q >> 12;
    const float r2 = (float)(0.08 * 0.08);
    const float cx = newxyz[q * 3 + 0];
    const float cy = newxyz[q * 3 + 1];
    const float cz = newxyz[q * 3 + 2];
    const float* xb = xyz + (size_t)b * NPTS * 3;

    int found = 0;
    int idx0 = 0;
    for (int base = 0; base < NPTS; base += 64) {
        int p = base + lane;
        float dx = xb[p * 3 + 0] - cx;
        float dy = xb[p * 3 + 1] - cy;
        float dz = xb[p * 3 + 2] - cz;
        float d2 = (dx * dx + dy * dy) + dz * dz;   // contract(off)
        bool valid = d2 < r2;
        unsigned long long mask = __ballot(valid);
        if (mask) {
            if (found == 0) idx0 = base + (__ffsll(mask) - 1);
            int rank = found + __popcll(mask & ((1ull << lane) - 1ull));
            if (valid && rank < NSAMP) idxout[(size_t)q * NSAMP + rank] = p;
            found += (int)__popcll(mask);
            if (found >= NSAMP) break;
        }
    }
    if (found < NSAMP) {
        int pad = (found > 0) ? idx0 : 0;
        if (found + lane < NSAMP) idxout[(size_t)q * NSAMP + found + lane] = pad;
    }
    if (lane == 0) cntout[q] = found;
}

// ---------------------------------------------------------------------------
// Fused gather + 3-layer 1x1-conv MLP + masked max-pool.
// One wave per group; X/Y tiles in LDS (row stride 36 floats, conflict-free
// float4 access); weights streamed from global (L1-resident); explicit fmaf.
// ---------------------------------------------------------------------------
__global__ __launch_bounds__(128) void mlp_kernel(
    const float* __restrict__ xyz, const float* __restrict__ newxyz,
    const float* __restrict__ ftr, const int* __restrict__ idxbuf,
    const int* __restrict__ cntbuf, const float* __restrict__ W0p,
    const float* __restrict__ b0, const float* __restrict__ W1,
    const float* __restrict__ b1, const float* __restrict__ W2,
    const float* __restrict__ b2, float* __restrict__ outfeat)
{
    __shared__ float sX[2][68 * 36];
    __shared__ float sY[2][64 * 36];
    const int w    = threadIdx.x >> 6;
    const int lane = threadIdx.x & 63;
    const int g = blockIdx.x * 2 + w;
    const int b = g >> 12;
    const int s = g & (SS - 1);
    float* X = sX[w];
    float* Y = sY[w];

    const int n = lane & 31, h = lane >> 5;
    const int pidx = idxbuf[(size_t)g * NSAMP + n];
    const float cx = newxyz[g * 3 + 0];
    const float cy = newxyz[g * 3 + 1];
    const float cz = newxyz[g * 3 + 2];

    if (h == 0) {
        const float* p = xyz + ((size_t)b * NPTS + pidx) * 3;
        X[0 * 36 + n] = p[0] - cx;
        X[1 * 36 + n] = p[1] - cy;
        X[2 * 36 + n] = p[2] - cz;
        X[67 * 36 + n] = 0.f;
    }
    {
        const float4* f4 = (const float4*)(ftr + ((size_t)b * NPTS + pidx) * CIN + h * 32);
        #pragma unroll
        for (int j = 0; j < 8; ++j) {
            float4 v = f4[j];
            int c = 3 + h * 32 + j * 4;
            X[(c + 0) * 36 + n] = v.x;
            X[(c + 1) * 36 + n] = v.y;
            X[(c + 2) * 36 + n] = v.z;
            X[(c + 3) * 36 + n] = v.w;
        }
    }
    __syncthreads();

    const int og = lane >> 3, ng = lane & 7;

    // ---- Layer 0: 67(->68) -> 64
    float acc0[8][4];
    #pragma unroll
    for (int j = 0; j < 8; ++j)
        #pragma unroll
        for (int nn = 0; nn < 4; ++nn) acc0[j][nn] = 0.f;
    for (int cb = 0; cb < 17; ++cb) {
        const int c = cb * 4;
        float4 xr0 = *(const float4*)&X[(c + 0) * 36 + ng * 4];
        float4 xr1 = *(const float4*)&X[(c + 1) * 36 + ng * 4];
        float4 xr2 = *(const float4*)&X[(c + 2) * 36 + ng * 4];
        float4 xr3 = *(const float4*)&X[(c + 3) * 36 + ng * 4];
        #pragma unroll
        for (int j = 0; j < 8; ++j) {
            float4 wv = *(const float4*)&W0p[(size_t)(og * 8 + j) * 68 + c];
            acc0[j][0] = fmaf(wv.x, xr0.x, acc0[j][0]);
            acc0[j][1] = fmaf(wv.x, xr0.y, acc0[j][1]);
            acc0[j][2] = fmaf(wv.x, xr0.z, acc0[j][2]);
            acc0[j][3] = fmaf(wv.x, xr0.w, acc0[j][3]);
            acc0[j][0] = fmaf(wv.y, xr1.x, acc0[j][0]);
            acc0[j][1] = fmaf(wv.y, xr1.y, acc0[j][1]);
            acc0[j][2] = fmaf(wv.y, xr1.z, acc0[j][2]);
            acc0[j][3] = fmaf(wv.y, xr1.w, acc0[j][3]);
            acc0[j][0] = fmaf(wv.z, xr2.x, acc0[j][0]);
            acc0[j][1] = fmaf(wv.z, xr2.y, acc0[j][1]);
            acc0[j][2] = fmaf(wv.z, xr2.z, acc0[j][2]);
            acc0[j][3] = fmaf(wv.z, xr2.w, acc0[j][3]);
            acc0[j][0] = fmaf(wv.w, xr3.x, acc0[j][0]);
            acc0[j][1] = fmaf(wv.w, xr3.y, acc0[j][1]);
            acc0[j][2] = fmaf(wv.w, xr3.z, acc0[j][2]);
            acc0[j][3] = fmaf(wv.w, xr3.w, acc0[j][3]);
        }
    }
    #pragma unroll
    for (int j = 0; j < 8; ++j) {
        const float bv = b0[og * 8 + j];
        float4 yv;
        yv.x = fmaxf(acc0[j][0] + bv, 0.f);
        yv.y = fmaxf(acc0[j][1] + bv, 0.f);
        yv.z = fmaxf(acc0[j][2] + bv, 0.f);
        yv.w = fmaxf(acc0[j][3] + bv, 0.f);
        *(float4*)&Y[(og * 8 + j) * 36 + ng * 4] = yv;
    }
    __syncthreads();

    // ---- Layer 1: 64 -> 64  (Y -> X rows 0..63)
    float acc1[8][4];
    #pragma unroll
    for (int j = 0; j < 8; ++j)
        #pragma unroll
        for (int nn = 0; nn < 4; ++nn) acc1[j][nn] = 0.f;
    for (int cb = 0; cb < 16; ++cb) {
        const int c = cb * 4;
        float4 xr0 = *(const float4*)&Y[(c + 0) * 36 + ng * 4];
        float4 xr1 = *(const float4*)&Y[(c + 1) * 36 + ng * 4];
        float4 xr2 = *(const float4*)&Y[(c + 2) * 36 + ng * 4];
        float4 xr3 = *(const float4*)&Y[(c + 3) * 36 + ng * 4];
        #pragma unroll
        for (int j = 0; j < 8; ++j) {
            float4 wv = *(const float4*)&W1[(size_t)(og * 8 + j) * 64 + c];
            acc1[j][0] = fmaf(wv.x, xr0.x, acc1[j][0]);
            acc1[j][1] = fmaf(wv.x, xr0.y, acc1[j][1]);
            acc1[j][2] = fmaf(wv.x, xr0.z, acc1[j][2]);
            acc1[j][3] = fmaf(wv.x, xr0.w, acc1[j][3]);
            acc1[j][0] = fmaf(wv.y, xr1.x, acc1[j][0]);
            acc1[j][1] = fmaf(wv.y, xr1.y, acc1[j][1]);
            acc1[j][2] = fmaf(wv.y, xr1.z, acc1[j][2]);
            acc1[j][3] = fmaf(wv.y, xr1.w, acc1[j][3]);
            acc1[j][0] = fmaf(wv.z, xr2.x, acc1[j][0]);
            acc1[j][1] = fmaf(wv.z, xr2.y, acc1[j][1]);
            acc1[j][2] = fmaf(wv.z, xr2.z, acc1[j][2]);
            acc1[j][3] = fmaf(wv.z, xr2.w, acc1[j][3]);
            acc1[j][0] = fmaf(wv.w, xr3.x, acc1[j][0]);
            acc1[j][1] = fmaf(wv.w, xr3.y, acc1[j][1]);
            acc1[j][2] = fmaf(wv.w, xr3.z, acc1[j][2]);
            acc1[j][3] = fmaf(wv.w, xr3.w, acc1[j][3]);
        }
    }
    __syncthreads();   // X rows are about to be overwritten; Y reads done
    #pragma unroll
    for (int j = 0; j < 8; ++j) {
        const float bv = b1[og * 8 + j];
        float4 yv;
        yv.x = fmaxf(acc1[j][0] + bv, 0.f);
        yv.y = fmaxf(acc1[j][1] + bv, 0.f);
        yv.z = fmaxf(acc1[j][2] + bv, 0.f);
        yv.w = fmaxf(acc1[j][3] + bv, 0.f);
        *(float4*)&X[(og * 8 + j) * 36 + ng * 4] = yv;
    }
    __syncthreads();

    // ---- Layer 2: 64 -> 128 (X rows 0..63 -> registers) + masked max-pool
    float acc2[16][4];
    #pragma unroll
    for (int j = 0; j < 16; ++j)
        #pragma unroll
        for (int nn = 0; nn < 4; ++nn) acc2[j][nn] = 0.f;
    for (int cb = 0; cb < 16; ++cb) {
        const int c = cb * 4;
        float4 xr0 = *(const float4*)&X[(c + 0) * 36 + ng * 4];
        float4 xr1 = *(const float4*)&X[(c + 1) * 36 + ng * 4];
        float4 xr2 = *(const float4*)&X[(c + 2) * 36 + ng * 4];
        float4 xr3 = *(const float4*)&X[(c + 3) * 36 + ng * 4];
        #pragma unroll
        for (int j = 0; j < 16; ++j) {
            float4 wv = *(const float4*)&W2[(size_t)(og * 16 + j) * 64 + c];
            acc2[j][0] = fmaf(wv.x, xr0.x, acc2[j][0]);
            acc2[j][1] = fmaf(wv.x, xr0.y, acc2[j][1]);
            acc2[j][2] = fmaf(wv.x, xr0.z, acc2[j][2]);
            acc2[j][3] = fmaf(wv.x, xr0.w, acc2[j][3]);
            acc2[j][0] = fmaf(wv.y, xr1.x, acc2[j][0]);
            acc2[j][1] = fmaf(wv.y, xr1.y, acc2[j][1]);
            acc2[j][2] = fmaf(wv.y, xr1.z, acc2[j][2]);
            acc2[j][3] = fmaf(wv.y, xr1.w, acc2[j][3]);
            acc2[j][0] = fmaf(wv.z, xr2.x, acc2[j][0]);
            acc2[j][1] = fmaf(wv.z, xr2.y, acc2[j][1]);
            acc2[j][2] = fmaf(wv.z, xr2.z, acc2[j][2]);
            acc2[j][3] = fmaf(wv.z, xr2.w, acc2[j][3]);
            acc2[j][0] = fmaf(wv.w, xr3.x, acc2[j][0]);
            acc2[j][1] = fmaf(wv.w, xr3.y, acc2[j][1]);
            acc2[j][2] = fmaf(wv.w, xr3.z, acc2[j][2]);
            acc2[j][3] = fmaf(wv.w, xr3.w, acc2[j][3]);
        }
    }

    const int cnt = cntbuf[g];
    const float msk = (cnt > 0) ? 1.f : 0.f;
    float* ob = outfeat + ((size_t)b * 128) * SS + s;
    float mj[16];
    #pragma unroll
    for (int j = 0; j < 16; ++j) {
        const float bv = b2[og * 16 + j];
        float v0 = fmaxf(acc2[j][0] + bv, acc2[j][1] + bv);
        float v1 = fmaxf(acc2[j][2] + bv, acc2[j][3] + bv);
        float v = fmaxf(fmaxf(v0, v1), 0.f);
        v = fmaxf(v, __shfl_xor(v, 1));
        v = fmaxf(v, __shfl_xor(v, 2));
        v = fmaxf(v, __shfl_xor(v, 4));
        mj[j] = v * msk;
    }
    if (ng == 0) {
        #pragma unroll
        for (int j = 0; j < 16; ++j)
            ob[(size_t)(og * 16 + j) * SS] = mj[j];
    }
}

// ---------------------------------------------------------------------------
extern "C" void kernel_launch(void* const* d_in, const int* in_sizes, int n_in,
                              void* d_out, int out_size, void* d_ws, size_t ws_size,
                              hipStream_t stream)
{
    (void)in_sizes; (void)n_in; (void)out_size; (void)ws_size;
    const float* xyz  = (const float*)d_in[0];
    const float* feat = (const float*)d_in[1];
    const float* W0 = (const float*)d_in[2];
    const float* b0 = (const float*)d_in[3];
    const float* W1 = (const float*)d_in[4];
    const float* b1 = (const float*)d_in[5];
    const float* W2 = (const float*)d_in[6];
    const float* b2 = (const float*)d_in[7];

    float* out     = (float*)d_out;
    float* newxyz  = out;                          // (B,S,3)
    float* outfeat = out + (size_t)BATCH * SS * 3; // (B,128,S)

    char* ws = (char*)d_ws;
    float* ftr = (float*)ws;                                   // B*N*64 f32 (8 MB)
    size_t off = (size_t)BATCH * NPTS * CIN * sizeof(float);
    int* idxbuf = (int*)(ws + off); off += (size_t)BATCH * SS * NSAMP * sizeof(int);
    int* cntbuf = (int*)(ws + off); off += (size_t)BATCH * SS * sizeof(int);
    float* W0p  = (float*)(ws + off);

    prep_kernel<<<dim3(BATCH * (NPTS / 64) + 1), dim3(256), 0, stream>>>(feat, W0, ftr, W0p);
    fps_kernel<<<dim3(BATCH), dim3(1024), 0, stream>>>(xyz, newxyz);
    bq_kernel<<<dim3(BATCH * SS / 4), dim3(256), 0, stream>>>(xyz, newxyz, idxbuf, cntbuf);
    mlp_kernel<<<dim3(BATCH * SS / 2), dim3(128), 0, stream>>>(
        xyz, newxyz, ftr, idxbuf, cntbuf, W0p, b0, W1, b1, W2, b2, outfeat);
}

// Round 7
// 8827.985 us; speedup vs baseline: 1.8926x; 1.0026x over previous
//
#include <hip/hip_runtime.h>

#pragma clang fp contract(off)

#define BATCH 2
#define NPTS  16384
#define SS    4096
#define NSAMP 32
#define CIN   64

// ---------------------------------------------------------------------------
// prep: transpose features (B,64,N) -> (B,N,64); pack W0 (64x67) -> (64x68, 0-pad)
// ---------------------------------------------------------------------------
__global__ __launch_bounds__(256) void prep_kernel(
    const float* __restrict__ feat, const float* __restrict__ W0,
    float* __restrict__ ftr, float* __restrict__ W0p)
{
    __shared__ float tl[64][65];
    const int t = threadIdx.x;
    const int blk = blockIdx.x;
    if (blk < BATCH * (NPTS / 64)) {
        const int b  = blk / (NPTS / 64);
        const int n0 = (blk % (NPTS / 64)) * 64;
        #pragma unroll
        for (int k = 0; k < 16; ++k) {
            int c = k * 4 + (t >> 6);
            int n = t & 63;
            tl[c][n] = feat[((size_t)b * CIN + c) * NPTS + n0 + n];
        }
        __syncthreads();
        #pragma unroll
        for (int k = 0; k < 16; ++k) {
            int n = k * 4 + (t >> 6);
            int c = t & 63;
            ftr[((size_t)b * NPTS + n0 + n) * CIN + c] = tl[c][n];
        }
    } else {
        for (int i = t; i < 64 * 68; i += 256) {
            int r = i / 68, c = i % 68;
            W0p[i] = (c < 67) ? W0[r * 67 + c] : 0.f;
        }
    }
}

// ---------------------------------------------------------------------------
// FPS: one block per batch, 1024 threads x 16 points in REGISTERS.
// r5 post-mortem: VGPR=40 showed LLVM rematerializes the const-__restrict__
// point loads every step (48 global re-loads/thread/step, ~196KB/step via L1)
// instead of keeping them resident. The empty "+v" asm pins below make each
// element an opaque VGPR def -> not rematerializable -> forced residency.
// Budget: 64 (pts) + 16 (md) + ~25 working < 128 (launch_bounds 1024,4).
// Exact FP semantics: contract off, ((dx2+dy2)+dz2), tie-break smallest idx.
// ---------------------------------------------------------------------------
__global__ __launch_bounds__(1024, 4) void fps_kernel(
    const float* __restrict__ xyz, float* __restrict__ newxyz)
{
    #pragma clang fp contract(off)
    const int b = blockIdx.x;
    const int t = threadIdx.x;
    const float* xb = xyz + (size_t)b * NPTS * 3;

    float px[16], py[16], pz[16], md[16];
    #pragma unroll
    for (int k = 0; k < 16; ++k) {
        int p = (k << 10) + t;
        px[k] = xb[p * 3 + 0];
        py[k] = xb[p * 3 + 1];
        pz[k] = xb[p * 3 + 2];
        md[k] = 1e10f;
    }
    // Pin coordinates into VGPRs: defeat load-rematerialization (r5: VGPR=40).
    #pragma unroll
    for (int k = 0; k < 16; ++k)
        asm volatile("" : "+v"(px[k]), "+v"(py[k]), "+v"(pz[k]));

    __shared__ float2 s_w[2][16];   // (best_val, best_idx as bits) per wave

    float lx = xb[0], ly = xb[1], lz = xb[2];
    if (t == 0) {
        float* o = newxyz + (size_t)b * SS * 3;
        o[0] = lx; o[1] = ly; o[2] = lz;
    }

    for (int s = 1; s < SS; ++s) {
        float bv = -1.f;
        int bi = 0;
        #pragma unroll
        for (int k = 0; k < 16; ++k) {
            float dx = px[k] - lx, dy = py[k] - ly, dz = pz[k] - lz;
            float d = (dx * dx + dy * dy) + dz * dz;   // contract(off): exact order
            float m = md[k];
            m = d < m ? d : m;
            md[k] = m;
            if (m > bv) { bv = m; bi = (k << 10) + t; }
        }

        // wave butterfly argmax, payload (bv, bi) only
        #pragma unroll
        for (int m = 1; m < 64; m <<= 1) {
            float ov = __shfl_xor(bv, m);
            int   oi = __shfl_xor(bi, m);
            bool take = (ov > bv) || (ov == bv && oi < bi);
            if (take) { bv = ov; bi = oi; }
        }

        const int pb = s & 1;
        if ((t & 63) == 0)
            s_w[pb][t >> 6] = make_float2(bv, __int_as_float(bi));
        __syncthreads();

        // every wave redundantly reduces the 16 wave-winners (no 2nd barrier;
        // double buffer pb prevents WAR across the single barrier)
        float2 rw = s_w[pb][t & 15];
        float rv = rw.x;
        int   ri = __float_as_int(rw.y);
        #pragma unroll
        for (int m = 1; m < 16; m <<= 1) {
            float ov = __shfl_xor(rv, m);
            int   oi = __shfl_xor(ri, m);
            bool take = (ov > rv) || (ov == rv && oi < ri);
            if (take) { rv = ov; ri = oi; }
        }

        // winner coords from global (same memory the carried regs came from;
        // wave-uniform address -> scalar load, L1/L2-resident)
        const int wi = __builtin_amdgcn_readfirstlane(ri);
        lx = xb[wi * 3 + 0];
        ly = xb[wi * 3 + 1];
        lz = xb[wi * 3 + 2];
        if (t == 0) {
            float* o = newxyz + ((size_t)b * SS + s) * 3;
            o[0] = lx; o[1] = ly; o[2] = lz;
        }
    }
}

// ---------------------------------------------------------------------------
// Ball query: one wave per query. First NSAMP valid indices in index order,
// pad with first valid, cnt flag. Exact FP compare semantics.
// ---------------------------------------------------------------------------
__global__ __launch_bounds__(256) void bq_kernel(
    const float* __restrict__ xyz, const float* __restrict__ newxyz,
    int* __restrict__ idxout, int* __restrict__ cntout)
{
    #pragma clang fp contract(off)
    const int lane = threadIdx.x & 63;
    const int q = blockIdx.x * 4 + (threadIdx.x >> 6);
    const int b = q >> 12;
    const float r2 = (float)(0.08 * 0.08);
    const float cx = newxyz[q * 3 + 0];
    const float cy = newxyz[q * 3 + 1];
    const float cz = newxyz[q * 3 + 2];
    const float* xb = xyz + (size_t)b * NPTS * 3;

    int found = 0;
    int idx0 = 0;
    for (int base = 0; base < NPTS; base += 64) {
        int p = base + lane;
        float dx = xb[p * 3 + 0] - cx;
        float dy = xb[p * 3 + 1] - cy;
        float dz = xb[p * 3 + 2] - cz;
        float d2 = (dx * dx + dy * dy) + dz * dz;   // contract(off)
        bool valid = d2 < r2;
        unsigned long long mask = __ballot(valid);
        if (mask) {
            if (found == 0) idx0 = base + (__ffsll(mask) - 1);
            int rank = found + __popcll(mask & ((1ull << lane) - 1ull));
            if (valid && rank < NSAMP) idxout[(size_t)q * NSAMP + rank] = p;
            found += (int)__popcll(mask);
            if (found >= NSAMP) break;
        }
    }
    if (found < NSAMP) {
        int pad = (found > 0) ? idx0 : 0;
        if (found + lane < NSAMP) idxout[(size_t)q * NSAMP + found + lane] = pad;
    }
    if (lane == 0) cntout[q] = found;
}

// ---------------------------------------------------------------------------
// Fused gather + 3-layer 1x1-conv MLP + masked max-pool.
// One wave per group; X/Y tiles in LDS (row stride 36 floats, conflict-free
// float4 access); weights streamed from global (L1-resident); explicit fmaf.
// ---------------------------------------------------------------------------
__global__ __launch_bounds__(128) void mlp_kernel(
    const float* __restrict__ xyz, const float* __restrict__ newxyz,
    const float* __restrict__ ftr, const int* __restrict__ idxbuf,
    const int* __restrict__ cntbuf, const float* __restrict__ W0p,
    const float* __restrict__ b0, const float* __restrict__ W1,
    const float* __restrict__ b1, const float* __restrict__ W2,
    const float* __restrict__ b2, float* __restrict__ outfeat)
{
    __shared__ float sX[2][68 * 36];
    __shared__ float sY[2][64 * 36];
    const int w    = threadIdx.x >> 6;
    const int lane = threadIdx.x & 63;
    const int g = blockIdx.x * 2 + w;
    const int b = g >> 12;
    const int s = g & (SS - 1);
    float* X = sX[w];
    float* Y = sY[w];

    const int n = lane & 31, h = lane >> 5;
    const int pidx = idxbuf[(size_t)g * NSAMP + n];
    const float cx = newxyz[g * 3 + 0];
    const float cy = newxyz[g * 3 + 1];
    const float cz = newxyz[g * 3 + 2];

    if (h == 0) {
        const float* p = xyz + ((size_t)b * NPTS + pidx) * 3;
        X[0 * 36 + n] = p[0] - cx;
        X[1 * 36 + n] = p[1] - cy;
        X[2 * 36 + n] = p[2] - cz;
        X[67 * 36 + n] = 0.f;
    }
    {
        const float4* f4 = (const float4*)(ftr + ((size_t)b * NPTS + pidx) * CIN + h * 32);
        #pragma unroll
        for (int j = 0; j < 8; ++j) {
            float4 v = f4[j];
            int c = 3 + h * 32 + j * 4;
            X[(c + 0) * 36 + n] = v.x;
            X[(c + 1) * 36 + n] = v.y;
            X[(c + 2) * 36 + n] = v.z;
            X[(c + 3) * 36 + n] = v.w;
        }
    }
    __syncthreads();

    const int og = lane >> 3, ng = lane & 7;

    // ---- Layer 0: 67(->68) -> 64
    float acc0[8][4];
    #pragma unroll
    for (int j = 0; j < 8; ++j)
        #pragma unroll
        for (int nn = 0; nn < 4; ++nn) acc0[j][nn] = 0.f;
    for (int cb = 0; cb < 17; ++cb) {
        const int c = cb * 4;
        float4 xr0 = *(const float4*)&X[(c + 0) * 36 + ng * 4];
        float4 xr1 = *(const float4*)&X[(c + 1) * 36 + ng * 4];
        float4 xr2 = *(const float4*)&X[(c + 2) * 36 + ng * 4];
        float4 xr3 = *(const float4*)&X[(c + 3) * 36 + ng * 4];
        #pragma unroll
        for (int j = 0; j < 8; ++j) {
            float4 wv = *(const float4*)&W0p[(size_t)(og * 8 + j) * 68 + c];
            acc0[j][0] = fmaf(wv.x, xr0.x, acc0[j][0]);
            acc0[j][1] = fmaf(wv.x, xr0.y, acc0[j][1]);
            acc0[j][2] = fmaf(wv.x, xr0.z, acc0[j][2]);
            acc0[j][3] = fmaf(wv.x, xr0.w, acc0[j][3]);
            acc0[j][0] = fmaf(wv.y, xr1.x, acc0[j][0]);
            acc0[j][1] = fmaf(wv.y, xr1.y, acc0[j][1]);
            acc0[j][2] = fmaf(wv.y, xr1.z, acc0[j][2]);
            acc0[j][3] = fmaf(wv.y, xr1.w, acc0[j][3]);
            acc0[j][0] = fmaf(wv.z, xr2.x, acc0[j][0]);
            acc0[j][1] = fmaf(wv.z, xr2.y, acc0[j][1]);
            acc0[j][2] = fmaf(wv.z, xr2.z, acc0[j][2]);
            acc0[j][3] = fmaf(wv.z, xr2.w, acc0[j][3]);
            acc0[j][0] = fmaf(wv.w, xr3.x, acc0[j][0]);
            acc0[j][1] = fmaf(wv.w, xr3.y, acc0[j][1]);
            acc0[j][2] = fmaf(wv.w, xr3.z, acc0[j][2]);
            acc0[j][3] = fmaf(wv.w, xr3.w, acc0[j][3]);
        }
    }
    #pragma unroll
    for (int j = 0; j < 8; ++j) {
        const float bv = b0[og * 8 + j];
        float4 yv;
        yv.x = fmaxf(acc0[j][0] + bv, 0.f);
        yv.y = fmaxf(acc0[j][1] + bv, 0.f);
        yv.z = fmaxf(acc0[j][2] + bv, 0.f);
        yv.w = fmaxf(acc0[j][3] + bv, 0.f);
        *(float4*)&Y[(og * 8 + j) * 36 + ng * 4] = yv;
    }
    __syncthreads();

    // ---- Layer 1: 64 -> 64  (Y -> X rows 0..63)
    float acc1[8][4];
    #pragma unroll
    for (int j = 0; j < 8; ++j)
        #pragma unroll
        for (int nn = 0; nn < 4; ++nn) acc1[j][nn] = 0.f;
    for (int cb = 0; cb < 16; ++cb) {
        const int c = cb * 4;
        float4 xr0 = *(const float4*)&Y[(c + 0) * 36 + ng * 4];
        float4 xr1 = *(const float4*)&Y[(c + 1) * 36 + ng * 4];
        float4 xr2 = *(const float4*)&Y[(c + 2) * 36 + ng * 4];
        float4 xr3 = *(const float4*)&Y[(c + 3) * 36 + ng * 4];
        #pragma unroll
        for (int j = 0; j < 8; ++j) {
            float4 wv = *(const float4*)&W1[(size_t)(og * 8 + j) * 64 + c];
            acc1[j][0] = fmaf(wv.x, xr0.x, acc1[j][0]);
            acc1[j][1] = fmaf(wv.x, xr0.y, acc1[j][1]);
            acc1[j][2] = fmaf(wv.x, xr0.z, acc1[j][2]);
            acc1[j][3] = fmaf(wv.x, xr0.w, acc1[j][3]);
            acc1[j][0] = fmaf(wv.y, xr1.x, acc1[j][0]);
            acc1[j][1] = fmaf(wv.y, xr1.y, acc1[j][1]);
            acc1[j][2] = fmaf(wv.y, xr1.z, acc1[j][2]);
            acc1[j][3] = fmaf(wv.y, xr1.w, acc1[j][3]);
            acc1[j][0] = fmaf(wv.z, xr2.x, acc1[j][0]);
            acc1[j][1] = fmaf(wv.z, xr2.y, acc1[j][1]);
            acc1[j][2] = fmaf(wv.z, xr2.z, acc1[j][2]);
            acc1[j][3] = fmaf(wv.z, xr2.w, acc1[j][3]);
            acc1[j][0] = fmaf(wv.w, xr3.x, acc1[j][0]);
            acc1[j][1] = fmaf(wv.w, xr3.y, acc1[j][1]);
            acc1[j][2] = fmaf(wv.w, xr3.z, acc1[j][2]);
            acc1[j][3] = fmaf(wv.w, xr3.w, acc1[j][3]);
        }
    }
    __syncthreads();   // X rows are about to be overwritten; Y reads done
    #pragma unroll
    for (int j = 0; j < 8; ++j) {
        const float bv = b1[og * 8 + j];
        float4 yv;
        yv.x = fmaxf(acc1[j][0] + bv, 0.f);
        yv.y = fmaxf(acc1[j][1] + bv, 0.f);
        yv.z = fmaxf(acc1[j][2] + bv, 0.f);
        yv.w = fmaxf(acc1[j][3] + bv, 0.f);
        *(float4*)&X[(og * 8 + j) * 36 + ng * 4] = yv;
    }
    __syncthreads();

    // ---- Layer 2: 64 -> 128 (X rows 0..63 -> registers) + masked max-pool
    float acc2[16][4];
    #pragma unroll
    for (int j = 0; j < 16; ++j)
        #pragma unroll
        for (int nn = 0; nn < 4; ++nn) acc2[j][nn] = 0.f;
    for (int cb = 0; cb < 16; ++cb) {
        const int c = cb * 4;
        float4 xr0 = *(const float4*)&X[(c + 0) * 36 + ng * 4];
        float4 xr1 = *(const float4*)&X[(c + 1) * 36 + ng * 4];
        float4 xr2 = *(const float4*)&X[(c + 2) * 36 + ng * 4];
        float4 xr3 = *(const float4*)&X[(c + 3) * 36 + ng * 4];
        #pragma unroll
        for (int j = 0; j < 16; ++j) {
            float4 wv = *(const float4*)&W2[(size_t)(og * 16 + j) * 64 + c];
            acc2[j][0] = fmaf(wv.x, xr0.x, acc2[j][0]);
            acc2[j][1] = fmaf(wv.x, xr0.y, acc2[j][1]);
            acc2[j][2] = fmaf(wv.x, xr0.z, acc2[j][2]);
            acc2[j][3] = fmaf(wv.x, xr0.w, acc2[j][3]);
            acc2[j][0] = fmaf(wv.y, xr1.x, acc2[j][0]);
            acc2[j][1] = fmaf(wv.y, xr1.y, acc2[j][1]);
            acc2[j][2] = fmaf(wv.y, xr1.z, acc2[j][2]);
            acc2[j][3] = fmaf(wv.y, xr1.w, acc2[j][3]);
            acc2[j][0] = fmaf(wv.z, xr2.x, acc2[j][0]);
            acc2[j][1] = fmaf(wv.z, xr2.y, acc2[j][1]);
            acc2[j][2] = fmaf(wv.z, xr2.z, acc2[j][2]);
            acc2[j][3] = fmaf(wv.z, xr2.w, acc2[j][3]);
            acc2[j][0] = fmaf(wv.w, xr3.x, acc2[j][0]);
            acc2[j][1] = fmaf(wv.w, xr3.y, acc2[j][1]);
            acc2[j][2] = fmaf(wv.w, xr3.z, acc2[j][2]);
            acc2[j][3] = fmaf(wv.w, xr3.w, acc2[j][3]);
        }
    }

    const int cnt = cntbuf[g];
    const float msk = (cnt > 0) ? 1.f : 0.f;
    float* ob = outfeat + ((size_t)b * 128) * SS + s;
    float mj[16];
    #pragma unroll
    for (int j = 0; j < 16; ++j) {
        const float bv = b2[og * 16 + j];
        float v0 = fmaxf(acc2[j][0] + bv, acc2[j][1] + bv);
        float v1 = fmaxf(acc2[j][2] + bv, acc2[j][3] + bv);
        float v = fmaxf(fmaxf(v0, v1), 0.f);
        v = fmaxf(v, __shfl_xor(v, 1));
        v = fmaxf(v, __shfl_xor(v, 2));
        v = fmaxf(v, __shfl_xor(v, 4));
        mj[j] = v * msk;
    }
    if (ng == 0) {
        #pragma unroll
        for (int j = 0; j < 16; ++j)
            ob[(size_t)(og * 16 + j) * SS] = mj[j];
    }
}

// ---------------------------------------------------------------------------
extern "C" void kernel_launch(void* const* d_in, const int* in_sizes, int n_in,
                              void* d_out, int out_size, void* d_ws, size_t ws_size,
                              hipStream_t stream)
{
    (void)in_sizes; (void)n_in; (void)out_size; (void)ws_size;
    const float* xyz  = (const float*)d_in[0];
    const float* feat = (const float*)d_in[1];
    const float* W0 = (const float*)d_in[2];
    const float* b0 = (const float*)d_in[3];
    const float* W1 = (const float*)d_in[4];
    const float* b1 = (const float*)d_in[5];
    const float* W2 = (const float*)d_in[6];
    const float* b2 = (const float*)d_in[7];

    float* out     = (float*)d_out;
    float* newxyz  = out;                          // (B,S,3)
    float* outfeat = out + (size_t)BATCH * SS * 3; // (B,128,S)

    char* ws = (char*)d_ws;
    float* ftr = (float*)ws;                                   // B*N*64 f32 (8 MB)
    size_t off = (size_t)BATCH * NPTS * CIN * sizeof(float);
    int* idxbuf = (int*)(ws + off); off += (size_t)BATCH * SS * NSAMP * sizeof(int);
    int* cntbuf = (int*)(ws + off); off += (size_t)BATCH * SS * sizeof(int);
    float* W0p  = (float*)(ws + off);

    prep_kernel<<<dim3(BATCH * (NPTS / 64) + 1), dim3(256), 0, stream>>>(feat, W0, ftr, W0p);
    fps_kernel<<<dim3(BATCH), dim3(1024), 0, stream>>>(xyz, newxyz);
    bq_kernel<<<dim3(BATCH * SS / 4), dim3(256), 0, stream>>>(xyz, newxyz, idxbuf, cntbuf);
    mlp_kernel<<<dim3(BATCH * SS / 2), dim3(128), 0, stream>>>(
        xyz, newxyz, ftr, idxbuf, cntbuf, W0p, b0, W1, b1, W2, b2, outfeat);
}